// Round 3
// baseline (254.881 us; speedup 1.0000x reference)
//
#include <hip/hip_runtime.h>

typedef unsigned short u16;
typedef unsigned int u32;
typedef __attribute__((ext_vector_type(8))) short bf16x8;
typedef __attribute__((ext_vector_type(4))) float f32x4;
typedef __attribute__((ext_vector_type(8))) u16 u16x8;

__device__ __forceinline__ u16 f2b(float f){
  u32 u = __float_as_uint(f);
  u32 r = (u + 0x7fffu + ((u >> 16) & 1u)) >> 16;
  return (u16)r;
}
__device__ __forceinline__ float b2f(u16 h){ return __uint_as_float(((u32)h) << 16); }

typedef const __attribute__((address_space(1))) void gvoid;
typedef __attribute__((address_space(3))) void svoid;
__device__ __forceinline__ void gl_lds16(const void* g, void* l){
  __builtin_amdgcn_global_load_lds((gvoid*)g, (svoid*)l, 16, 0, 0);
}

// ---------------- convert x f32 -> bf16 (vectorized 8/thread) ----------------
__global__ void conv_f2b(const float* __restrict__ in, u16* __restrict__ out, int n8){
  int i = blockIdx.x * 256 + threadIdx.x;
  if(i >= n8) return;
  f32x4 a = *(const f32x4*)(in + (size_t)i*8);
  f32x4 b = *(const f32x4*)(in + (size_t)i*8 + 4);
  u16x8 o;
  #pragma unroll
  for(int j=0;j<4;j++){ o[j] = f2b(a[j]); o[4+j] = f2b(b[j]); }
  *(u16x8*)(out + (size_t)i*8) = o;
}

// ------------- transpose-convert weights: in R x C f32 -> out C x R bf16 -----
__global__ void tconv(const float* __restrict__ in, u16* __restrict__ out, int R, int C){
  __shared__ __align__(16) float tile[64*68];
  int gc = C >> 6;
  int rt = blockIdx.x / gc, ct = blockIdx.x % gc;
  int r0 = rt*64, c0 = ct*64;
  int tid = threadIdx.x;
  #pragma unroll
  for(int it=0; it<4; it++){
    int idx = tid + it*256;
    int rl = idx >> 4, cseg = idx & 15;
    f32x4 v = *(const f32x4*)(in + (size_t)(r0+rl)*C + c0 + cseg*4);
    *(f32x4*)&tile[rl*68 + cseg*4] = v;
  }
  __syncthreads();
  #pragma unroll
  for(int it=0; it<2; it++){
    int idx = tid + it*256;
    int cl = idx >> 3, rseg = idx & 7;
    u16x8 o;
    #pragma unroll
    for(int j=0;j<8;j++) o[j] = f2b(tile[(rseg*8+j)*68 + cl]);
    *(u16x8*)(out + (size_t)(c0+cl)*R + r0 + rseg*8) = o;
  }
}

// ---------------- GEMM: A(MxK) bf16 row-major, Bt(NxK) bf16 row-major --------
// EPI=0: store bf16 C (MxN).  EPI=1: store f32 C + bias[col].
template<int EPI>
__global__ __launch_bounds__(256,2) void gemm_bt(const u16* __restrict__ A, const u16* __restrict__ Bt,
                                                 void* __restrict__ Cp, const float* __restrict__ bias,
                                                 int M, int N, int K){
  __shared__ __align__(16) u16 As[128*32];
  __shared__ __align__(16) u16 Bs[128*32];
  int tid = threadIdx.x, lane = tid & 63, w = tid >> 6;
  int nb = N >> 7;
  int bm = blockIdx.x / nb, bn = blockIdx.x % nb;
  int m0 = bm*128, n0 = bn*128;
  int wm = (w >> 1)*64, wn = (w & 1)*64;
  int l16 = lane & 15, lg = lane >> 4;
  f32x4 acc[4][4];
  #pragma unroll
  for(int i=0;i<4;i++)
    #pragma unroll
    for(int j=0;j<4;j++) acc[i][j] = (f32x4){0.f,0.f,0.f,0.f};

  for(int kk=0; kk<K; kk+=32){
    #pragma unroll
    for(int it=0; it<2; it++){
      int id = tid + it*256;
      int row = id >> 2, seg = id & 3;
      gl_lds16(A  + (size_t)(m0+row)*K + kk + seg*8, &As[id*8]);
      gl_lds16(Bt + (size_t)(n0+row)*K + kk + seg*8, &Bs[id*8]);
    }
    __syncthreads();
    bf16x8 af[4], bfr[4];
    #pragma unroll
    for(int i=0;i<4;i++) af[i]  = *(const bf16x8*)&As[(wm + i*16 + l16)*32 + lg*8];
    #pragma unroll
    for(int j=0;j<4;j++) bfr[j] = *(const bf16x8*)&Bs[(wn + j*16 + l16)*32 + lg*8];
    #pragma unroll
    for(int i=0;i<4;i++)
      #pragma unroll
      for(int j=0;j<4;j++)
        acc[i][j] = __builtin_amdgcn_mfma_f32_16x16x32_bf16(af[i], bfr[j], acc[i][j], 0,0,0);
    __syncthreads();
  }
  #pragma unroll
  for(int i=0;i<4;i++)
    #pragma unroll
    for(int j=0;j<4;j++){
      int col = n0 + wn + j*16 + l16;
      #pragma unroll
      for(int r=0;r<4;r++){
        int row = m0 + wm + i*16 + lg*4 + r;
        float v = acc[i][j][r];
        if(EPI == 0) ((u16*)Cp)[(size_t)row*N + col] = f2b(v);
        else         ((float*)Cp)[(size_t)row*N + col] = v + bias[col];
      }
    }
}

// ------- scatter qkv -> Q (scaled by 0.125, +bias) and K (+bias), (b,h,n,d) --
__global__ void scatter_qk(const u16* __restrict__ qkv, const float* __restrict__ bqkv,
                           u16* __restrict__ Qs, u16* __restrict__ Ks){
  int v = blockIdx.x * 256 + threadIdx.x;       // 0 .. 1048575
  int which = v >> 19;                          // 0=q, 1=k
  int idx8 = v & 524287;
  int o = idx8 << 3;                            // elem base in (b,h,n,d)
  int b = o >> 21, h = (o >> 17) & 15, n = (o >> 6) & 2047, d0 = o & 63;
  const u16* src = qkv + (size_t)(b*2048 + n)*3072 + which*1024 + h*64 + d0;
  u16x8 raw = *(const u16x8*)src;
  const float* bp = bqkv + which*1024 + h*64 + d0;
  f32x4 b0 = *(const f32x4*)bp, b1 = *(const f32x4*)(bp + 4);
  float scale = (which == 0) ? 0.125f : 1.0f;
  u16x8 ov;
  #pragma unroll
  for(int j=0;j<4;j++){
    ov[j]   = f2b((b2f(raw[j])   + b0[j]) * scale);
    ov[4+j] = f2b((b2f(raw[4+j]) + b1[j]) * scale);
  }
  u16* dst = (which ? Ks : Qs) + o;
  *(u16x8*)dst = ov;
}

// ---------------- V -> Vt (b,h,d,n) via LDS tile transpose -------------------
__global__ void transpose_v(const u16* __restrict__ qkv, u16* __restrict__ Vt){
  __shared__ __align__(16) u16 tile[64*72];
  int nt = blockIdx.x & 31, bh = blockIdx.x >> 5;
  int b = bh >> 4, h = bh & 15;
  int n0 = nt*64;
  int tid = threadIdx.x;
  const u16* src = qkv + (size_t)(b*2048)*3072 + 2048 + h*64;
  #pragma unroll
  for(int it=0; it<2; it++){
    int idx = tid + it*256;
    int nl = idx >> 3, dseg = idx & 7;
    u16x8 vv = *(const u16x8*)(src + (size_t)(n0+nl)*3072 + dseg*8);
    *(u16x8*)&tile[nl*72 + dseg*8] = vv;
  }
  __syncthreads();
  u16* dst = Vt + (size_t)bh*64*2048;
  #pragma unroll
  for(int it=0; it<2; it++){
    int idx = tid + it*256;
    int dl = idx >> 3, nseg = idx & 7;
    u16x8 o;
    #pragma unroll
    for(int j=0;j<8;j++) o[j] = tile[(nseg*8+j)*72 + dl];
    *(u16x8*)(dst + (size_t)dl*2048 + n0 + nseg*8) = o;
  }
}

// ---------------- fused attention with head-axis softmax ---------------------
// Grid: B * (N/32) * KSPLIT = 256 blocks, 512 threads (8 waves, 2 heads/wave).
#define PROW 56
__global__ __launch_bounds__(512,2) void attn_kernel(const u16* __restrict__ Q, const u16* __restrict__ Kg,
                                                     const u16* __restrict__ Vt, u16* __restrict__ Op){
  __shared__ __align__(16) u16 Pall[16*32*PROW];   // exp(S) per head, padded rows
  __shared__ __align__(16) float rZs[32*36];       // 1/Z per (q,k)
  const int tid = threadIdx.x, lane = tid & 63, w = tid >> 6;
  const int l16 = lane & 15, lg = lane >> 4;
  const int bid = blockIdx.x;
  const int split = bid & 1, qt = (bid >> 1) & 63, b = bid >> 7;
  const int q0 = qt*32;
  const int kbase = split*1024;

  // Q fragments (SCALE pre-folded): [head][qsub][dchunk]
  bf16x8 qf[2][2][2];
  #pragma unroll
  for(int hh=0;hh<2;hh++){
    int h = w*2 + hh;
    const u16* Qh = Q + ((size_t)(b*16 + h)*2048 + q0)*64;
    #pragma unroll
    for(int qs=0;qs<2;qs++)
      #pragma unroll
      for(int dc=0;dc<2;dc++)
        qf[hh][qs][dc] = *(const bf16x8*)(Qh + (qs*16 + l16)*64 + dc*32 + lg*8);
  }
  f32x4 Oa[2][2][4];
  #pragma unroll
  for(int a=0;a<2;a++)
    #pragma unroll
    for(int c=0;c<2;c++)
      #pragma unroll
      for(int d=0;d<4;d++) Oa[a][c][d] = (f32x4){0.f,0.f,0.f,0.f};

  for(int kt=0; kt<32; kt++){
    int k0 = kbase + kt*32;
    // --- S = (Q*scale) K^T, exp, write to Pall ---
    #pragma unroll
    for(int hh=0;hh<2;hh++){
      int h = w*2 + hh;
      const u16* Kh = Kg + ((size_t)(b*16 + h)*2048 + k0)*64;
      f32x4 S[2][2];
      #pragma unroll
      for(int qs=0;qs<2;qs++)
        #pragma unroll
        for(int ks=0;ks<2;ks++) S[qs][ks] = (f32x4){0.f,0.f,0.f,0.f};
      #pragma unroll
      for(int ks=0;ks<2;ks++)
        #pragma unroll
        for(int dc=0;dc<2;dc++){
          bf16x8 kf = *(const bf16x8*)(Kh + (ks*16 + l16)*64 + dc*32 + lg*8);
          #pragma unroll
          for(int qs=0;qs<2;qs++)
            S[qs][ks] = __builtin_amdgcn_mfma_f32_16x16x32_bf16(qf[hh][qs][dc], kf, S[qs][ks], 0,0,0);
        }
      u16* Ph = &Pall[(h*32)*PROW];
      #pragma unroll
      for(int qs=0;qs<2;qs++)
        #pragma unroll
        for(int ks=0;ks<2;ks++){
          int q = qs*16 + lg*4;
          int k = ks*16 + l16;
          #pragma unroll
          for(int r=0;r<4;r++){
            float e = __expf(S[qs][ks][r]);
            Ph[(q + r)*PROW + k] = f2b(e);
          }
        }
    }
    __syncthreads();
    // --- Z = sum over heads; rZ = 1/Z ---
    #pragma unroll
    for(int rr=0; rr<2; rr++){
      int ee = tid + rr*512;
      int q = ee >> 5, k = ee & 31;
      float z = 0.f;
      #pragma unroll
      for(int h=0; h<16; h++) z += b2f(Pall[(h*32 + q)*PROW + k]);
      rZs[q*36 + k] = 1.0f / z;
    }
    __syncthreads();
    // --- PV: O += (P * rZ) @ V ---
    #pragma unroll
    for(int hh=0;hh<2;hh++){
      int h = w*2 + hh;
      const u16* Vh = Vt + (size_t)(b*16 + h)*64*2048;
      bf16x8 pf[2];
      #pragma unroll
      for(int qs=0;qs<2;qs++){
        int q = qs*16 + l16;
        bf16x8 praw = *(const bf16x8*)&Pall[(h*32 + q)*PROW + lg*8];
        const float* rzp = &rZs[q*36 + lg*8];
        f32x4 rz0 = *(const f32x4*)rzp;
        f32x4 rz1 = *(const f32x4*)(rzp + 4);
        bf16x8 pv;
        #pragma unroll
        for(int j=0;j<4;j++){
          pv[j]   = (short)f2b(b2f((u16)praw[j])   * rz0[j]);
          pv[4+j] = (short)f2b(b2f((u16)praw[4+j]) * rz1[j]);
        }
        pf[qs] = pv;
      }
      #pragma unroll
      for(int ds=0;ds<4;ds++){
        bf16x8 vf = *(const bf16x8*)(Vh + (size_t)(ds*16 + l16)*2048 + k0 + lg*8);
        #pragma unroll
        for(int qs=0;qs<2;qs++)
          Oa[hh][qs][ds] = __builtin_amdgcn_mfma_f32_16x16x32_bf16(pf[qs], vf, Oa[hh][qs][ds], 0,0,0);
      }
    }
    __syncthreads();
  }
  // epilogue: O -> Op[split] in (b, n, h*64+d) bf16
  u16* Ob = Op + (size_t)split*4194304;
  #pragma unroll
  for(int hh=0;hh<2;hh++){
    int h = w*2 + hh;
    #pragma unroll
    for(int qs=0;qs<2;qs++)
      #pragma unroll
      for(int ds=0;ds<4;ds++){
        int col = h*64 + ds*16 + l16;
        #pragma unroll
        for(int r=0;r<4;r++){
          int row = q0 + qs*16 + lg*4 + r;
          Ob[(size_t)(b*2048 + row)*1024 + col] = f2b(Oa[hh][qs][ds][r]);
        }
      }
  }
}

// ---------------- combine k-split partials -> bf16 w_avg ---------------------
__global__ void combine2(const u16* __restrict__ a, const u16* __restrict__ b, u16* __restrict__ o){
  int i = blockIdx.x * 256 + threadIdx.x;
  u16x8 va = ((const u16x8*)a)[i], vb = ((const u16x8*)b)[i];
  u16x8 vo;
  #pragma unroll
  for(int j=0;j<8;j++) vo[j] = f2b(b2f(va[j]) + b2f(vb[j]));
  ((u16x8*)o)[i] = vo;
}

extern "C" void kernel_launch(void* const* d_in, const int* in_sizes, int n_in,
                              void* d_out, int out_size, void* d_ws, size_t ws_size,
                              hipStream_t stream){
  const float* x      = (const float*)d_in[0];
  const float* w_qkv  = (const float*)d_in[1];
  const float* b_qkv  = (const float*)d_in[2];
  const float* w_proj = (const float*)d_in[3];
  const float* b_proj = (const float*)d_in[4];
  float* out = (float*)d_out;
  char* ws = (char*)d_ws;

  u16* xb   = (u16*)(ws);                 // 8.4 MB  (reused as w_avg later)
  u16* wqT  = (u16*)(ws + 8388608);       // 6.3 MB
  u16* wpT  = (u16*)(ws + 14680064);      // 2.1 MB
  u16* Qs   = (u16*)(ws + 16777216);      // 8.4 MB
  u16* Ks   = (u16*)(ws + 25165824);      // 8.4 MB
  u16* Vt   = (u16*)(ws + 33554432);      // 8.4 MB
  u16* qkvb = (u16*)(ws + 41943040);      // 25.2 MB (reused as Op0/Op1)
  u16* Op0  = qkvb;
  u16* Op1  = qkvb + 4194304;
  u16* wavg = xb;

  conv_f2b<<<2048, 256, 0, stream>>>(x, xb, 524288);
  tconv<<<768, 256, 0, stream>>>(w_qkv, wqT, 1024, 3072);
  tconv<<<256, 256, 0, stream>>>(w_proj, wpT, 1024, 1024);
  gemm_bt<0><<<768, 256, 0, stream>>>(xb, wqT, (void*)qkvb, nullptr, 4096, 3072, 1024);
  scatter_qk<<<4096, 256, 0, stream>>>(qkvb, b_qkv, Qs, Ks);
  transpose_v<<<1024, 256, 0, stream>>>(qkvb, Vt);
  attn_kernel<<<256, 512, 0, stream>>>(Qs, Ks, Vt, Op0);
  combine2<<<2048, 256, 0, stream>>>(Op0, Op1, wavg);
  gemm_bt<1><<<256, 256, 0, stream>>>(wavg, wpT, (void*)out, b_proj, 4096, 1024, 1024);
}